// Round 11
// baseline (238.240 us; speedup 1.0000x reference)
//
#include <hip/hip_runtime.h>

// CascadeHierarchicalEmbedding, R11 = R10 (NT emb0) + 2x resident waves via
// 8-token tiles.
// - per-wave LDS staging: 3 tables x 2 KB (8 tokens); block = 16 KB WF +
//   4 waves x 6 KB = 40 KB -> 4 blocks/CU = 16 waves/CU (was 8).
// - MFMA token columns 8..15 are duplicates of 0..7 (reads row t16&7);
//   stores masked to t16<8. Wasted VALU/MFMA is free (machine 79% idle).
// - counted vmcnt: loop vmcnt(10) (= ids6 + stores4), prologue vmcnt(6).
// - all else identical to R10: NT on emb0 gathers only, XOR-swizzled
//   global_load_lds, plain merged stores, W1 frags in shared LDS.

#define WPB 4        // waves per block (256 threads)
#define NBLK 1024    // 1024 blocks x 4 waves = 4096 waves = 4 blocks/CU

#define AUX_NT 2     // gfx940+ CPol: sc0=1, nt=2, sc1=16

typedef float f32x4 __attribute__((ext_vector_type(4)));
typedef short v8s __attribute__((ext_vector_type(8)));
typedef __attribute__((address_space(3))) uint32_t lds_u32_t;
typedef __attribute__((address_space(1))) const uint32_t glb_u32_t;

static __device__ __forceinline__ unsigned short bf16_rne(float f) {
  union { float f; unsigned int u; } a; a.f = f;
  return (unsigned short)((a.u + 0x7FFFu + ((a.u >> 16) & 1u)) >> 16);
}

// Pack W1 (f32 [128][32]) into bf16 A-fragments (W1^T). gate0: frags 0..7,
// gate1: frags 8..15. fragid = gate*8 + kt*2 + nt; elem (lane,j):
// k = kt*32 + (lane>>4)*8 + j, o = nt*16 + (lane&15) -> w1[k][o].
__global__ __launch_bounds__(256) void prep_frags(
    const float* __restrict__ g0w1, const float* __restrict__ g1w1,
    unsigned short* __restrict__ wsf) {
  int t = blockIdx.x * 256 + threadIdx.x;
  if (t >= 1024) return;
  int lane = t & 63, fragid = t >> 6;
  int gate = fragid >> 3, kt = (fragid >> 1) & 3, nt = fragid & 1;
  const float* __restrict__ w1 = gate ? g1w1 : g0w1;
#pragma unroll
  for (int j = 0; j < 8; ++j) {
    int k = kt * 32 + ((lane >> 4) << 3) + j;
    int o = nt * 16 + (lane & 15);
    wsf[fragid * 512 + lane * 8 + j] = bf16_rne(w1[k * 32 + o]);
  }
}

// One gate level: z = W1^T x (bf16-hi), W frags JIT-read from LDS in pairs;
// relu+layer2 per lane, 2-shuffle reduce, sigmoid, blend cur in place.
static __device__ __forceinline__ void gate_apply(
    const float (&fine)[16], float (&cur)[16], const uint4* wfl, int lane,
    f32x4 b1a, f32x4 b1b, f32x4 w2a, f32x4 w2b, float b2s) {
  v8s xf0, xf1, xc0, xc1;
#pragma unroll
  for (int e = 0; e < 8; ++e) {
    xf0[e] = (short)bf16_rne(fine[e]);
    xf1[e] = (short)bf16_rne(fine[8 + e]);
    xc0[e] = (short)bf16_rne(cur[e]);
    xc1[e] = (short)bf16_rne(cur[8 + e]);
  }
  f32x4 acc0 = b1a, acc1 = b1b;
  {
    uint4 wa = wfl[0 * 64 + lane], wb = wfl[1 * 64 + lane];
    acc0 = __builtin_amdgcn_mfma_f32_16x16x32_bf16(*(const v8s*)&wa, xf0, acc0, 0, 0, 0);
    acc1 = __builtin_amdgcn_mfma_f32_16x16x32_bf16(*(const v8s*)&wb, xf0, acc1, 0, 0, 0);
  }
  {
    uint4 wa = wfl[2 * 64 + lane], wb = wfl[3 * 64 + lane];
    acc0 = __builtin_amdgcn_mfma_f32_16x16x32_bf16(*(const v8s*)&wa, xf1, acc0, 0, 0, 0);
    acc1 = __builtin_amdgcn_mfma_f32_16x16x32_bf16(*(const v8s*)&wb, xf1, acc1, 0, 0, 0);
  }
  {
    uint4 wa = wfl[4 * 64 + lane], wb = wfl[5 * 64 + lane];
    acc0 = __builtin_amdgcn_mfma_f32_16x16x32_bf16(*(const v8s*)&wa, xc0, acc0, 0, 0, 0);
    acc1 = __builtin_amdgcn_mfma_f32_16x16x32_bf16(*(const v8s*)&wb, xc0, acc1, 0, 0, 0);
  }
  {
    uint4 wa = wfl[6 * 64 + lane], wb = wfl[7 * 64 + lane];
    acc0 = __builtin_amdgcn_mfma_f32_16x16x32_bf16(*(const v8s*)&wa, xc1, acc0, 0, 0, 0);
    acc1 = __builtin_amdgcn_mfma_f32_16x16x32_bf16(*(const v8s*)&wb, xc1, acc1, 0, 0, 0);
  }
  float zp = 0.f;
#pragma unroll
  for (int j = 0; j < 4; ++j)
    zp += fmaxf(acc0[j], 0.f) * w2a[j] + fmaxf(acc1[j], 0.f) * w2b[j];
  zp += __shfl_xor(zp, 16);
  zp += __shfl_xor(zp, 32);
  float g = 1.f / (1.f + __expf(-(zp + b2s)));
#pragma unroll
  for (int e = 0; e < 16; ++e) cur[e] = fmaf(g, fine[e] - cur[e], cur[e]);
}

__global__ __launch_bounds__(256, 4) void cascade_pipe(
    const int* __restrict__ ids0, const int* __restrict__ ids1,
    const int* __restrict__ ids2,
    const float* __restrict__ emb0, const float* __restrict__ emb1,
    const float* __restrict__ emb2,
    const uint4* __restrict__ wfrag,
    const float* __restrict__ b1_0, const float* __restrict__ w2_0,
    const float* __restrict__ b2_0,
    const float* __restrict__ b1_1, const float* __restrict__ w2_1,
    const float* __restrict__ b2_1,
    float* __restrict__ out, int n) {
  __shared__ uint4 WF[1024];            // 16 KB: frag f at WF[f*64 + lane]
  __shared__ float4 EB[WPB][3][128];    // per wave: emb2 | emb1 | emb0, 2 KB ea
  const int tid = threadIdx.x, lane = tid & 63, wave = tid >> 6;
  const int q = lane >> 4, t16 = lane & 15;
  const int r8 = t16 & 7;               // physical row in 8-token tile
  const int ntiles = n >> 3;            // 8 tokens per tile
  const int nw = NBLK * WPB;
  int tile = blockIdx.x * WPB + wave;
  if (tile >= ntiles) return;
  float4* myF = &EB[wave][0][0];

  // stage W fragments into LDS (256 thr x 4 x 16 B = 16 KB, linear)
#pragma unroll
  for (int k = 0; k < 4; ++k)
    __builtin_amdgcn_global_load_lds(
        (glb_u32_t*)((const char*)wfrag + (k * 256 + tid) * 16),
        (lds_u32_t*)(uint32_t*)&WF[k * 256 + tid], 16, 0, 0);

  // layer-2 params (per-lane, q-dependent)
  const f32x4 b1a0 = *(const f32x4*)&b1_0[q * 4], b1b0 = *(const f32x4*)&b1_0[16 + q * 4];
  const f32x4 w2a0 = *(const f32x4*)&w2_0[q * 4], w2b0 = *(const f32x4*)&w2_0[16 + q * 4];
  const f32x4 b1a1 = *(const f32x4*)&b1_1[q * 4], b1b1 = *(const f32x4*)&b1_1[16 + q * 4];
  const f32x4 w2a1 = *(const f32x4*)&w2_1[q * 4], w2b1 = *(const f32x4*)&w2_1[16 + q * 4];
  const float b2s0 = b2_0[0], b2s1 = b2_1[0];

  int jA0[2], jA1[2], jA2[2];   // gather ids for the NEXT tile to issue

  // 6 id loads for a tile (per-lane rows s*4+q of the 8-token tile)
  auto loadids = [&](int t, int (&i0)[2], int (&i1)[2], int (&i2)[2]) {
    int tb = (t << 3) + q;
#pragma unroll
    for (int s = 0; s < 2; ++s) {
      i0[s] = ids0[tb + s * 4];
      i1[s] = ids1[tb + s * 4];
      i2[s] = ids2[tb + s * 4];
    }
  };
  // 6 direct-to-LDS gathers, XOR-swizzled via pre-swizzled global source.
  // emb0 (256 MB table, streaming, no reuse) carries NT.
  auto issue6 = [&](const int (&i0)[2], const int (&i1)[2], const int (&i2)[2]) {
#pragma unroll
    for (int s = 0; s < 2; ++s) {
      int swb = ((t16 ^ (s * 4 + q)) << 4);
      __builtin_amdgcn_global_load_lds(
          (glb_u32_t*)((const char*)emb2 + (((long)i2[s]) << 8) + swb),
          (lds_u32_t*)(uint32_t*)(myF + 0 * 128 + s * 64), 16, 0, 0);
      __builtin_amdgcn_global_load_lds(
          (glb_u32_t*)((const char*)emb1 + (((long)i1[s]) << 8) + swb),
          (lds_u32_t*)(uint32_t*)(myF + 1 * 128 + s * 64), 16, 0, 0);
      __builtin_amdgcn_global_load_lds(
          (glb_u32_t*)((const char*)emb0 + (((long)i0[s]) << 8) + swb),
          (lds_u32_t*)(uint32_t*)(myF + 2 * 128 + s * 64), 16, 0, AUX_NT);
    }
  };

  // ---- prologue: WF staged; gathers(tile0) in flight; jA = ids(tile0+nw)
  {
    int a0[2], a1[2], a2[2];
    loadids(tile, a0, a1, a2);
    __syncthreads();            // WF visible (drains all counters)
    issue6(a0, a1, a2);         // 6 gathers for tile0
    { int t2 = tile + nw; if (t2 >= ntiles) t2 = 0; loadids(t2, jA0, jA1, jA2); }
    asm volatile("s_waitcnt vmcnt(6)" ::: "memory");  // gathers(t0) done; ids fly
    __builtin_amdgcn_sched_barrier(0);
  }

  for (; tile < ntiles; tile += nw) {
    // steady state queue: gathers(6) | ids(6) | stores(4) -> vmcnt(10)
    asm volatile("s_waitcnt vmcnt(10)" ::: "memory");
    __builtin_amdgcn_sched_barrier(0);

    // pull this tile's fragments to registers (swizzled chunks of row r8;
    // lanes t16>=8 duplicate token t16-8 — results discarded at store)
    float curv[16], f1v[16], f0v[16];
#pragma unroll
    for (int e = 0; e < 4; ++e) {
      int ci = (2 * q + (e & 1) + 8 * (e >> 1)) ^ r8;
      *(float4*)&curv[e * 4] = myF[0 * 128 + r8 * 16 + ci];
      *(float4*)&f1v[e * 4]  = myF[1 * 128 + r8 * 16 + ci];
      *(float4*)&f0v[e * 4]  = myF[2 * 128 + r8 * 16 + ci];
    }
    asm volatile("s_waitcnt lgkmcnt(0)" ::: "memory");  // reads done -> LDS free
    __builtin_amdgcn_sched_barrier(0);

    // issue gathers for tile+nw (prefetch), then ids for tile+2nw
    issue6(jA0, jA1, jA2);
    { int t2 = tile + 2 * nw; if (t2 >= ntiles) t2 = 0; loadids(t2, jA0, jA1, jA2); }
    __builtin_amdgcn_sched_barrier(0);

    // gate level 1 (fine = emb1), then level 0 (fine = emb0); W from LDS
    gate_apply(f1v, curv, &WF[512], lane, b1a1, b1b1, w2a1, w2b1, b2s1);
    gate_apply(f0v, curv, &WF[0],   lane, b1a0, b1b0, w2a0, w2b0, b2s0);

    // store token (tile*8 + t16), t16<8 only: 4 x 16 B (plain; L2 merges)
    if (t16 < 8) {
      long tok = ((long)tile << 3) + t16;
      if (tok < n) {
        float4* op = (float4*)out + (tok << 4);
        op[2 * q + 0]     = float4{curv[0], curv[1], curv[2], curv[3]};
        op[2 * q + 1]     = float4{curv[4], curv[5], curv[6], curv[7]};
        op[8 + 2 * q + 0] = float4{curv[8], curv[9], curv[10], curv[11]};
        op[8 + 2 * q + 1] = float4{curv[12], curv[13], curv[14], curv[15]};
      }
    }
  }
}

extern "C" void kernel_launch(void* const* d_in, const int* in_sizes, int n_in,
                              void* d_out, int out_size, void* d_ws,
                              size_t ws_size, hipStream_t stream) {
  const int* ids0 = (const int*)d_in[0];
  const int* ids1 = (const int*)d_in[1];
  const int* ids2 = (const int*)d_in[2];
  const float* emb0 = (const float*)d_in[3];
  const float* emb1 = (const float*)d_in[4];
  const float* emb2 = (const float*)d_in[5];
  const float* g0w1 = (const float*)d_in[6];
  const float* g0b1 = (const float*)d_in[7];
  const float* g0w2 = (const float*)d_in[8];
  const float* g0b2 = (const float*)d_in[9];
  const float* g1w1 = (const float*)d_in[10];
  const float* g1b1 = (const float*)d_in[11];
  const float* g1w2 = (const float*)d_in[12];
  const float* g1b2 = (const float*)d_in[13];
  float* out = (float*)d_out;

  int n = in_sizes[0];  // B*H tokens

  hipLaunchKernelGGL(prep_frags, dim3(4), dim3(256), 0, stream,
                     g0w1, g1w1, (unsigned short*)d_ws);

  hipLaunchKernelGGL(cascade_pipe, dim3(NBLK), dim3(256), 0, stream,
                     ids0, ids1, ids2, emb0, emb1, emb2,
                     (const uint4*)d_ws,
                     g0b1, g0w2, g0b2,
                     g1b1, g1w2, g1b2,
                     out, n);
}

// Round 12
// 123.143 us; speedup vs baseline: 1.9347x; 1.9347x over previous
//
#include <hip/hip_runtime.h>

// CascadeHierarchicalEmbedding, R12 = exact revert to R10 (best: 123.2 us).
// R11 (8-token tiles, 16 waves/CU) falsified the concurrency lever: rate rose
// to 3.74 TB/s but FETCH exploded 273->648 MB (emb1 L3 reuse destroyed).
// R10 sits at the composed ceiling: FETCH ~250-273 MB (= compulsory floor:
// emb0 210 logical + emb1 26 distinct + emb2 2.5 + ids 10), WRITE 204.8 MB
// (= output exactly), sustained rate ~3.7 TB/s (= measured saturation of the
// 256-B random-gather + stream-write mix across R5/R9/R10/R11).
//
// Structure: all tables via swizzled global_load_lds into per-wave 4 KB LDS
// buffers (XOR-swizzled global source, linear LDS dest); NT cache policy on
// emb0 gathers only (streaming, evict-first -> protects emb1/emb2 residency);
// W1 bf16 fragments in shared LDS; counted-vmcnt prefetch pipeline (loop
// vmcnt(16) = ids12+stores4, never drains the 12 in-flight gathers); gates on
// mfma_f32_16x16x32_bf16 with swapped operands (gate scalar lands at
// col=token); plain merged stores.

#define WPB 4       // waves per block (256 threads)
#define NBLK 512    // 512 blocks x 4 waves = 2048 waves = 2 blocks/CU

#define AUX_NT 2    // gfx940+ CPol: sc0=1, nt=2, sc1=16

typedef float f32x4 __attribute__((ext_vector_type(4)));
typedef short v8s __attribute__((ext_vector_type(8)));
typedef __attribute__((address_space(3))) uint32_t lds_u32_t;
typedef __attribute__((address_space(1))) const uint32_t glb_u32_t;

static __device__ __forceinline__ unsigned short bf16_rne(float f) {
  union { float f; unsigned int u; } a; a.f = f;
  return (unsigned short)((a.u + 0x7FFFu + ((a.u >> 16) & 1u)) >> 16);
}

// Pack W1 (f32 [128][32]) into bf16 A-fragments (W1^T). gate0: frags 0..7,
// gate1: frags 8..15. fragid = gate*8 + kt*2 + nt; elem (lane,j):
// k = kt*32 + (lane>>4)*8 + j, o = nt*16 + (lane&15) -> w1[k][o].
__global__ __launch_bounds__(256) void prep_frags(
    const float* __restrict__ g0w1, const float* __restrict__ g1w1,
    unsigned short* __restrict__ wsf) {
  int t = blockIdx.x * 256 + threadIdx.x;
  if (t >= 1024) return;
  int lane = t & 63, fragid = t >> 6;
  int gate = fragid >> 3, kt = (fragid >> 1) & 3, nt = fragid & 1;
  const float* __restrict__ w1 = gate ? g1w1 : g0w1;
#pragma unroll
  for (int j = 0; j < 8; ++j) {
    int k = kt * 32 + ((lane >> 4) << 3) + j;
    int o = nt * 16 + (lane & 15);
    wsf[fragid * 512 + lane * 8 + j] = bf16_rne(w1[k * 32 + o]);
  }
}

// One gate level: z = W1^T x (bf16-hi), W frags JIT-read from LDS in pairs;
// relu+layer2 per lane, 2-shuffle reduce, sigmoid, blend cur in place.
static __device__ __forceinline__ void gate_apply(
    const float (&fine)[16], float (&cur)[16], const uint4* wfl, int lane,
    f32x4 b1a, f32x4 b1b, f32x4 w2a, f32x4 w2b, float b2s) {
  v8s xf0, xf1, xc0, xc1;
#pragma unroll
  for (int e = 0; e < 8; ++e) {
    xf0[e] = (short)bf16_rne(fine[e]);
    xf1[e] = (short)bf16_rne(fine[8 + e]);
    xc0[e] = (short)bf16_rne(cur[e]);
    xc1[e] = (short)bf16_rne(cur[8 + e]);
  }
  f32x4 acc0 = b1a, acc1 = b1b;
  {
    uint4 wa = wfl[0 * 64 + lane], wb = wfl[1 * 64 + lane];
    acc0 = __builtin_amdgcn_mfma_f32_16x16x32_bf16(*(const v8s*)&wa, xf0, acc0, 0, 0, 0);
    acc1 = __builtin_amdgcn_mfma_f32_16x16x32_bf16(*(const v8s*)&wb, xf0, acc1, 0, 0, 0);
  }
  {
    uint4 wa = wfl[2 * 64 + lane], wb = wfl[3 * 64 + lane];
    acc0 = __builtin_amdgcn_mfma_f32_16x16x32_bf16(*(const v8s*)&wa, xf1, acc0, 0, 0, 0);
    acc1 = __builtin_amdgcn_mfma_f32_16x16x32_bf16(*(const v8s*)&wb, xf1, acc1, 0, 0, 0);
  }
  {
    uint4 wa = wfl[4 * 64 + lane], wb = wfl[5 * 64 + lane];
    acc0 = __builtin_amdgcn_mfma_f32_16x16x32_bf16(*(const v8s*)&wa, xc0, acc0, 0, 0, 0);
    acc1 = __builtin_amdgcn_mfma_f32_16x16x32_bf16(*(const v8s*)&wb, xc0, acc1, 0, 0, 0);
  }
  {
    uint4 wa = wfl[6 * 64 + lane], wb = wfl[7 * 64 + lane];
    acc0 = __builtin_amdgcn_mfma_f32_16x16x32_bf16(*(const v8s*)&wa, xc1, acc0, 0, 0, 0);
    acc1 = __builtin_amdgcn_mfma_f32_16x16x32_bf16(*(const v8s*)&wb, xc1, acc1, 0, 0, 0);
  }
  float zp = 0.f;
#pragma unroll
  for (int j = 0; j < 4; ++j)
    zp += fmaxf(acc0[j], 0.f) * w2a[j] + fmaxf(acc1[j], 0.f) * w2b[j];
  zp += __shfl_xor(zp, 16);
  zp += __shfl_xor(zp, 32);
  float g = 1.f / (1.f + __expf(-(zp + b2s)));
#pragma unroll
  for (int e = 0; e < 16; ++e) cur[e] = fmaf(g, fine[e] - cur[e], cur[e]);
}

__global__ __launch_bounds__(256, 2) void cascade_pipe(
    const int* __restrict__ ids0, const int* __restrict__ ids1,
    const int* __restrict__ ids2,
    const float* __restrict__ emb0, const float* __restrict__ emb1,
    const float* __restrict__ emb2,
    const uint4* __restrict__ wfrag,
    const float* __restrict__ b1_0, const float* __restrict__ w2_0,
    const float* __restrict__ b2_0,
    const float* __restrict__ b1_1, const float* __restrict__ w2_1,
    const float* __restrict__ b2_1,
    float* __restrict__ out, int n) {
  __shared__ uint4 WF[1024];            // 16 KB: frag f at WF[f*64 + lane]
  __shared__ float4 EB[WPB][3][256];    // per wave: emb2 | emb1 | emb0, 4 KB ea
  const int tid = threadIdx.x, lane = tid & 63, wave = tid >> 6;
  const int q = lane >> 4, t16 = lane & 15;
  const int ntiles = n >> 4;
  const int nw = NBLK * WPB;
  int tile = blockIdx.x * WPB + wave;
  if (tile >= ntiles) return;
  float4* myF = &EB[wave][0][0];

  // stage W fragments into LDS (256 thr x 4 x 16 B = 16 KB, linear)
#pragma unroll
  for (int k = 0; k < 4; ++k)
    __builtin_amdgcn_global_load_lds(
        (glb_u32_t*)((const char*)wfrag + (k * 256 + tid) * 16),
        (lds_u32_t*)(uint32_t*)&WF[k * 256 + tid], 16, 0, 0);

  // layer-2 params (per-lane, q-dependent)
  const f32x4 b1a0 = *(const f32x4*)&b1_0[q * 4], b1b0 = *(const f32x4*)&b1_0[16 + q * 4];
  const f32x4 w2a0 = *(const f32x4*)&w2_0[q * 4], w2b0 = *(const f32x4*)&w2_0[16 + q * 4];
  const f32x4 b1a1 = *(const f32x4*)&b1_1[q * 4], b1b1 = *(const f32x4*)&b1_1[16 + q * 4];
  const f32x4 w2a1 = *(const f32x4*)&w2_1[q * 4], w2b1 = *(const f32x4*)&w2_1[16 + q * 4];
  const float b2s0 = b2_0[0], b2s1 = b2_1[0];

  int jA0[4], jA1[4], jA2[4];   // gather ids for the NEXT tile to issue

  // 12 id loads for a tile (per-lane rows s*4+q of the tile)
  auto loadids = [&](int t, int (&i0)[4], int (&i1)[4], int (&i2)[4]) {
    int tb = (t << 4) + q;
#pragma unroll
    for (int s = 0; s < 4; ++s) {
      i0[s] = ids0[tb + s * 4];
      i1[s] = ids1[tb + s * 4];
      i2[s] = ids2[tb + s * 4];
    }
  };
  // 12 direct-to-LDS gathers, XOR-swizzled via pre-swizzled global source.
  // emb0 (256 MB table, streaming, no reuse) carries NT so it doesn't evict
  // emb1/emb2 from L2/L3.
  auto issue12 = [&](const int (&i0)[4], const int (&i1)[4], const int (&i2)[4]) {
#pragma unroll
    for (int s = 0; s < 4; ++s) {
      int swb = ((t16 ^ (s * 4 + q)) << 4);
      __builtin_amdgcn_global_load_lds(
          (glb_u32_t*)((const char*)emb2 + (((long)i2[s]) << 8) + swb),
          (lds_u32_t*)(uint32_t*)(myF + 0 * 256 + s * 64), 16, 0, 0);
      __builtin_amdgcn_global_load_lds(
          (glb_u32_t*)((const char*)emb1 + (((long)i1[s]) << 8) + swb),
          (lds_u32_t*)(uint32_t*)(myF + 1 * 256 + s * 64), 16, 0, 0);
      __builtin_amdgcn_global_load_lds(
          (glb_u32_t*)((const char*)emb0 + (((long)i0[s]) << 8) + swb),
          (lds_u32_t*)(uint32_t*)(myF + 2 * 256 + s * 64), 16, 0, AUX_NT);
    }
  };

  // ---- prologue: WF staged; gathers(tile0) in flight; jA = ids(tile0+nw)
  {
    int a0[4], a1[4], a2[4];
    loadids(tile, a0, a1, a2);
    __syncthreads();            // WF visible (drains all counters)
    issue12(a0, a1, a2);        // 12 gathers for tile0
    { int t2 = tile + nw; if (t2 >= ntiles) t2 = 0; loadids(t2, jA0, jA1, jA2); }
    asm volatile("s_waitcnt vmcnt(12)" ::: "memory");  // gathers(t0) done; ids fly
    __builtin_amdgcn_sched_barrier(0);
  }

  for (; tile < ntiles; tile += nw) {
    // steady state queue: gathers(12) | ids(12) | stores(4) -> vmcnt(16)
    asm volatile("s_waitcnt vmcnt(16)" ::: "memory");
    __builtin_amdgcn_sched_barrier(0);

    // pull this tile's fragments to registers (swizzled chunks of row t16)
    float curv[16], f1v[16], f0v[16];
#pragma unroll
    for (int e = 0; e < 4; ++e) {
      int ci = (2 * q + (e & 1) + 8 * (e >> 1)) ^ t16;
      *(float4*)&curv[e * 4] = myF[0 * 256 + t16 * 16 + ci];
      *(float4*)&f1v[e * 4]  = myF[1 * 256 + t16 * 16 + ci];
      *(float4*)&f0v[e * 4]  = myF[2 * 256 + t16 * 16 + ci];
    }
    asm volatile("s_waitcnt lgkmcnt(0)" ::: "memory");  // reads done -> LDS free
    __builtin_amdgcn_sched_barrier(0);

    // issue gathers for tile+nw (prefetch), then ids for tile+2nw
    issue12(jA0, jA1, jA2);
    { int t2 = tile + 2 * nw; if (t2 >= ntiles) t2 = 0; loadids(t2, jA0, jA1, jA2); }
    __builtin_amdgcn_sched_barrier(0);

    // gate level 1 (fine = emb1), then level 0 (fine = emb0); W from LDS
    gate_apply(f1v, curv, &WF[512], lane, b1a1, b1b1, w2a1, w2b1, b2s1);
    gate_apply(f0v, curv, &WF[0],   lane, b1a0, b1b0, w2a0, w2b0, b2s0);

    // store token (tile*16 + t16): 4 x 16 B (plain stores; L2 merges lines)
    long tok = ((long)tile << 4) + t16;
    if (tok < n) {
      float4* op = (float4*)out + (tok << 4);
      op[2 * q + 0]     = float4{curv[0], curv[1], curv[2], curv[3]};
      op[2 * q + 1]     = float4{curv[4], curv[5], curv[6], curv[7]};
      op[8 + 2 * q + 0] = float4{curv[8], curv[9], curv[10], curv[11]};
      op[8 + 2 * q + 1] = float4{curv[12], curv[13], curv[14], curv[15]};
    }
  }
}

extern "C" void kernel_launch(void* const* d_in, const int* in_sizes, int n_in,
                              void* d_out, int out_size, void* d_ws,
                              size_t ws_size, hipStream_t stream) {
  const int* ids0 = (const int*)d_in[0];
  const int* ids1 = (const int*)d_in[1];
  const int* ids2 = (const int*)d_in[2];
  const float* emb0 = (const float*)d_in[3];
  const float* emb1 = (const float*)d_in[4];
  const float* emb2 = (const float*)d_in[5];
  const float* g0w1 = (const float*)d_in[6];
  const float* g0b1 = (const float*)d_in[7];
  const float* g0w2 = (const float*)d_in[8];
  const float* g0b2 = (const float*)d_in[9];
  const float* g1w1 = (const float*)d_in[10];
  const float* g1b1 = (const float*)d_in[11];
  const float* g1w2 = (const float*)d_in[12];
  const float* g1b2 = (const float*)d_in[13];
  float* out = (float*)d_out;

  int n = in_sizes[0];  // B*H tokens

  hipLaunchKernelGGL(prep_frags, dim3(4), dim3(256), 0, stream,
                     g0w1, g1w1, (unsigned short*)d_ws);

  hipLaunchKernelGGL(cascade_pipe, dim3(NBLK), dim3(256), 0, stream,
                     ids0, ids1, ids2, emb0, emb1, emb2,
                     (const uint4*)d_ws,
                     g0b1, g0w2, g0b2,
                     g1b1, g1w2, g1b2,
                     out, n);
}